// Round 1
// baseline (456.250 us; speedup 1.0000x reference)
//
#include <hip/hip_runtime.h>
#include <math.h>

// Problem constants (CausalSemanticGrouping): key [B,N,D] fp32, slot_embed [K,D] fp32
#define BB 64
#define NN 1024
#define DD 512
#define KK 64
#define CC 1088   // K + N

// d_out layout: out [B,K,D] then dots [B,K,C], fp32, flat-concatenated.
// d_ws layout (floats): rslot [0,64) | rkey [64, 64+B*N) | attn [64+B*N, +B*K*C)
//   total = 64 + 65536 + 4456448 floats = ~17.3 MiB

__device__ __forceinline__ float waveReduceSum(float v) {
    #pragma unroll
    for (int off = 32; off > 0; off >>= 1) v += __shfl_down(v, off, 64);
    return v;
}
__device__ __forceinline__ float waveReduceMax(float v) {
    #pragma unroll
    for (int off = 32; off > 0; off >>= 1) v = fmaxf(v, __shfl_down(v, off, 64));
    return v;
}

// 1 / max(||slot_k||, 1e-12). grid: K blocks x 64 threads (1 wave)
__global__ __launch_bounds__(64) void k_rslot(const float* __restrict__ slot,
                                              float* __restrict__ rslot) {
    int k = blockIdx.x;
    int lane = threadIdx.x;
    const float* row = slot + (size_t)k * DD;
    float s = 0.f;
    #pragma unroll
    for (int i = 0; i < DD / 64; i++) {
        float v = row[lane + i * 64];
        s += v * v;
    }
    s = waveReduceSum(s);
    if (lane == 0) rslot[k] = 1.0f / fmaxf(sqrtf(s), 1e-12f);
}

// 1 / max(||key_bn||, 1e-12). grid: B*N/4 blocks x 256 threads (4 waves, 1 row/wave)
__global__ __launch_bounds__(256) void k_rkey(const float* __restrict__ key,
                                              float* __restrict__ rkey) {
    int wave = threadIdx.x >> 6;
    int lane = threadIdx.x & 63;
    size_t row = (size_t)blockIdx.x * 4 + wave;
    const float4* p = (const float4*)(key + row * DD);  // 128 float4 per row
    float4 a = p[lane];
    float4 b = p[lane + 64];
    float s = a.x*a.x + a.y*a.y + a.z*a.z + a.w*a.w
            + b.x*b.x + b.y*b.y + b.z*b.z + b.w*b.w;
    s = waveReduceSum(s);
    if (lane == 0) rkey[row] = 1.0f / fmaxf(sqrtf(s), 1e-12f);
}

// dots[b, 0:64, c0:c0+64] = (slot · rowsT) scaled by rslot/rnorm.
// grid: (C/64, B), 256 threads, 4x4 microtile per thread.
__global__ __launch_bounds__(256) void k_dots(const float* __restrict__ key,
                                              const float* __restrict__ slot,
                                              const float* __restrict__ rslot,
                                              const float* __restrict__ rkey,
                                              float* __restrict__ dots) {
    __shared__ float As[64][33];  // [slot m][kk]   pad -> <=2-way (free)
    __shared__ float Bs[64][33];  // [col  c][kk]
    const int b = blockIdx.y;
    const int c0 = blockIdx.x * 64;
    const int tid = threadIdx.x;
    const int tm = tid >> 4, tn = tid & 15;
    float acc[4][4] = {};

    for (int k0 = 0; k0 < DD; k0 += 32) {
        #pragma unroll
        for (int i = 0; i < 8; i++) {
            int idx = tid + i * 256;        // 2048 = 64 rows x 32
            int r = idx >> 5, kk = idx & 31;
            As[r][kk] = slot[(size_t)r * DD + k0 + kk];
            int c = c0 + r;
            const float* vrow = (c < KK) ? (slot + (size_t)c * DD)
                                         : (key + ((size_t)b * NN + (c - KK)) * DD);
            Bs[r][kk] = vrow[k0 + kk];
        }
        __syncthreads();
        #pragma unroll
        for (int kk = 0; kk < 32; kk++) {
            float a[4], bv[4];
            #pragma unroll
            for (int i = 0; i < 4; i++) a[i] = As[tm * 4 + i][kk];
            #pragma unroll
            for (int j = 0; j < 4; j++) bv[j] = Bs[tn * 4 + j][kk];
            #pragma unroll
            for (int i = 0; i < 4; i++)
                #pragma unroll
                for (int j = 0; j < 4; j++) acc[i][j] += a[i] * bv[j];
        }
        __syncthreads();
    }

    // epilogue: scale by rslot[m] * rnorm(col), write float4
    int cbase = c0 + tn * 4;
    float rn[4];
    #pragma unroll
    for (int j = 0; j < 4; j++) {
        int c = cbase + j;
        rn[j] = (c < KK) ? rslot[c] : rkey[(size_t)b * NN + (c - KK)];
    }
    #pragma unroll
    for (int i = 0; i < 4; i++) {
        int m = tm * 4 + i;
        float rs = rslot[m];
        float4 o;
        o.x = acc[i][0] * rs * rn[0];
        o.y = acc[i][1] * rs * rn[1];
        o.z = acc[i][2] * rs * rn[2];
        o.w = acc[i][3] * rs * rn[3];
        *(float4*)(dots + ((size_t)b * KK + m) * CC + cbase) = o;
    }
}

// masked softmax(dots/TEMP) row-wise, then /(1+1e-7). grid: (K, B), 256 threads.
__global__ __launch_bounds__(256) void k_softmax(const float* __restrict__ dots,
                                                 float* __restrict__ attn) {
    const int k = blockIdx.x, b = blockIdx.y;
    const float* row = dots + ((size_t)b * KK + k) * CC;
    float* arow = attn + ((size_t)b * KK + k) * CC;
    const int tid = threadIdx.x;
    __shared__ float red[4];

    float vals[5];
    int cnt = 0;
    float m = -INFINITY;
    for (int c = tid; c < CC; c += 256) {
        bool ok = (c >= KK) || (c < k);   // strict lower-tri for slot-slot, all keys
        float x = ok ? (row[c] / 0.07f) : -INFINITY;
        vals[cnt++] = x;
        m = fmaxf(m, x);
    }
    m = waveReduceMax(m);
    if ((tid & 63) == 0) red[tid >> 6] = m;
    __syncthreads();
    m = fmaxf(fmaxf(red[0], red[1]), fmaxf(red[2], red[3]));

    float s = 0.f;
    cnt = 0;
    for (int c = tid; c < CC; c += 256) {
        float e = (vals[cnt] == -INFINITY) ? 0.0f : expf(vals[cnt] - m);
        vals[cnt] = e;
        s += e;
        cnt++;
    }
    s = waveReduceSum(s);
    __syncthreads();   // red[] reuse
    if ((tid & 63) == 0) red[tid >> 6] = s;
    __syncthreads();
    s = red[0] + red[1] + red[2] + red[3];

    // softmax sums to 1, so attn_n = (e/S) / (1 + 1e-7)
    float inv = 1.0f / (s * (1.0f + 1e-7f));
    cnt = 0;
    for (int c = tid; c < CC; c += 256) arow[c] = vals[cnt++] * inv;
}

// out[b, 0:64, d0:d0+64] = attn[b] (64xC) x V[b] (CxD).  grid: (D/64, B).
__global__ __launch_bounds__(256) void k_out(const float* __restrict__ key,
                                             const float* __restrict__ slot,
                                             const float* __restrict__ attn,
                                             float* __restrict__ out) {
    __shared__ float At[64][33];  // [slot m][cc]
    __shared__ float Vt[32][65];  // [cc][d]
    const int b = blockIdx.y;
    const int d0 = blockIdx.x * 64;
    const int tid = threadIdx.x;
    const int tm = tid >> 4, tn = tid & 15;
    float acc[4][4] = {};

    for (int ct = 0; ct < CC; ct += 32) {
        #pragma unroll
        for (int i = 0; i < 8; i++) {
            int idx = tid + i * 256;        // 2048 = 64 rows x 32
            int r = idx >> 5, cc2 = idx & 31;
            At[r][cc2] = attn[((size_t)b * KK + r) * CC + ct + cc2];
        }
        #pragma unroll
        for (int i = 0; i < 8; i++) {
            int idx = tid + i * 256;        // 2048 = 32 rows x 64
            int cc2 = idx >> 6, dd = idx & 63;
            int c = ct + cc2;
            const float* vrow = (c < KK) ? (slot + (size_t)c * DD)
                                         : (key + ((size_t)b * NN + (c - KK)) * DD);
            Vt[cc2][dd] = vrow[d0 + dd];
        }
        __syncthreads();
        #pragma unroll
        for (int cc2 = 0; cc2 < 32; cc2++) {
            float a[4], bv[4];
            #pragma unroll
            for (int i = 0; i < 4; i++) a[i] = At[tm * 4 + i][cc2];
            #pragma unroll
            for (int j = 0; j < 4; j++) bv[j] = Vt[cc2][tn * 4 + j];
            #pragma unroll
            for (int i = 0; i < 4; i++)
                #pragma unroll
                for (int j = 0; j < 4; j++) acc[i][j] += a[i] * bv[j];
        }
        __syncthreads();
    }

    #pragma unroll
    for (int i = 0; i < 4; i++) {
        int m = tm * 4 + i;
        float4 o = {acc[i][0], acc[i][1], acc[i][2], acc[i][3]};
        *(float4*)(out + ((size_t)b * KK + m) * DD + d0 + tn * 4) = o;
    }
}

extern "C" void kernel_launch(void* const* d_in, const int* in_sizes, int n_in,
                              void* d_out, int out_size, void* d_ws, size_t ws_size,
                              hipStream_t stream) {
    const float* key  = (const float*)d_in[0];   // [B, N, D]
    const float* slot = (const float*)d_in[1];   // [K, D]
    float* out  = (float*)d_out;                        // [B, K, D]
    float* dots = out + (size_t)BB * KK * DD;           // [B, K, C]
    float* ws = (float*)d_ws;
    float* rslot = ws;                                  // [K]
    float* rkey  = ws + 64;                             // [B*N]
    float* attn  = ws + 64 + (size_t)BB * NN;           // [B, K, C]

    k_rslot<<<dim3(KK), dim3(64), 0, stream>>>(slot, rslot);
    k_rkey<<<dim3(BB * NN / 4), dim3(256), 0, stream>>>(key, rkey);
    k_dots<<<dim3(CC / 64, BB), dim3(256), 0, stream>>>(key, slot, rslot, rkey, dots);
    k_softmax<<<dim3(KK, BB), dim3(256), 0, stream>>>(dots, attn);
    k_out<<<dim3(DD / 64, BB), dim3(256), 0, stream>>>(key, slot, attn, out);
}

// Round 3
// 292.157 us; speedup vs baseline: 1.5617x; 1.5617x over previous
//
#include <hip/hip_runtime.h>
#include <math.h>

// CausalSemanticGrouping: key [B,N,D] fp32, slot_embed [K,D] fp32
#define BB 64
#define NN 1024
#define DD 512
#define KK 64
#define CC 1088   // K + N

// d_out: out [B,K,D] fp32 then dots [B,K,C] fp32.
// d_ws (floats): rslot [0,64) | rkey [64, 64+B*N) | attn [64+B*N, +B*K*C)
//   total = 64 + 65536 + 4456448 floats = 17.25 MiB  (same as passing R1 layout)

typedef __bf16 bf16_t;
typedef __bf16 bf16x4 __attribute__((ext_vector_type(4)));
typedef __bf16 bf16x8 __attribute__((ext_vector_type(8)));
typedef float f32x16 __attribute__((ext_vector_type(16)));

__device__ __forceinline__ float waveReduceSum(float v) {
    #pragma unroll
    for (int off = 32; off > 0; off >>= 1) v += __shfl_down(v, off, 64);
    return v;
}
__device__ __forceinline__ float waveReduceMax(float v) {
    #pragma unroll
    for (int off = 32; off > 0; off >>= 1) v = fmaxf(v, __shfl_down(v, off, 64));
    return v;
}
// split x into bf16 hi + bf16 lo, x ~= hi + lo with ~2^-16 relative error
__device__ __forceinline__ void split4(float4 x, bf16x4& hi, bf16x4& lo) {
    float v[4] = {x.x, x.y, x.z, x.w};
    #pragma unroll
    for (int j = 0; j < 4; j++) {
        __bf16 h = (__bf16)v[j];
        hi[j] = h;
        lo[j] = (__bf16)(v[j] - (float)h);
    }
}

// 1 / max(||slot_k||, 1e-12). grid: K x 64 (1 wave/row)
__global__ __launch_bounds__(64) void k_rslot(const float* __restrict__ slot,
                                              float* __restrict__ rslot) {
    int k = blockIdx.x, lane = threadIdx.x;
    const float* row = slot + (size_t)k * DD;
    float s = 0.f;
    #pragma unroll
    for (int i = 0; i < DD / 64; i++) { float v = row[lane + i * 64]; s += v * v; }
    s = waveReduceSum(s);
    if (lane == 0) rslot[k] = 1.0f / fmaxf(sqrtf(s), 1e-12f);
}

// 1 / max(||key_bn||, 1e-12). grid: B*N/4 x 256 (1 wave/row)
__global__ __launch_bounds__(256) void k_rkey(const float* __restrict__ key,
                                              float* __restrict__ rkey) {
    int wave = threadIdx.x >> 6, lane = threadIdx.x & 63;
    size_t row = (size_t)blockIdx.x * 4 + wave;
    const float4* p = (const float4*)(key + row * DD);
    float4 a = p[lane], b = p[lane + 64];
    float s = a.x*a.x + a.y*a.y + a.z*a.z + a.w*a.w
            + b.x*b.x + b.y*b.y + b.z*b.z + b.w*b.w;
    s = waveReduceSum(s);
    if (lane == 0) rkey[row] = 1.0f / fmaxf(sqrtf(s), 1e-12f);
}

// dots[b, 0:64, ct*64:+64] via split-bf16 32x32x16 MFMA (3 mfma/k-step).
// grid (17, B) x 256.
__global__ __launch_bounds__(256) void k_dots(const float* __restrict__ key,
                                              const float* __restrict__ slot,
                                              const float* __restrict__ rslot,
                                              const float* __restrict__ rkey,
                                              float* __restrict__ dots) {
    __shared__ __align__(16) bf16_t Ahi[64][72], Alo[64][72];
    __shared__ __align__(16) bf16_t Bhi[64][72], Blo[64][72];
    __shared__ float sr[64];
    const int b = blockIdx.y, ct = blockIdx.x;
    const int tid = threadIdx.x;
    const int w = tid >> 6, lane = tid & 63;
    const int mw = (w >> 1) * 32, nw = (w & 1) * 32;
    if (tid < 64) sr[tid] = rslot[tid];
    f32x16 acc = {};

    for (int k0 = 0; k0 < DD; k0 += 64) {
        #pragma unroll
        for (int i = 0; i < 4; i++) {
            int idx = tid + i * 256;          // 1024 granules: 64 rows x 16 (x4 floats)
            int r = idx >> 4, g = idx & 15;
            float4 av = *(const float4*)&slot[(size_t)r * DD + k0 + g * 4];
            bf16x4 h, l;
            split4(av, h, l);
            *(bf16x4*)&Ahi[r][g * 4] = h;
            *(bf16x4*)&Alo[r][g * 4] = l;
            int c = ct * 64 + r;
            const float* src = (c < KK)
                ? &slot[(size_t)c * DD + k0 + g * 4]
                : &key[((size_t)b * NN + (c - KK)) * DD + k0 + g * 4];
            float4 bv = *(const float4*)src;
            split4(bv, h, l);
            *(bf16x4*)&Bhi[r][g * 4] = h;
            *(bf16x4*)&Blo[r][g * 4] = l;
        }
        __syncthreads();
        #pragma unroll
        for (int kk = 0; kk < 64; kk += 16) {
            bf16x8 ah = *(bf16x8*)&Ahi[mw + (lane & 31)][kk + (lane >> 5) * 8];
            bf16x8 al = *(bf16x8*)&Alo[mw + (lane & 31)][kk + (lane >> 5) * 8];
            bf16x8 bh = *(bf16x8*)&Bhi[nw + (lane & 31)][kk + (lane >> 5) * 8];
            bf16x8 bl = *(bf16x8*)&Blo[nw + (lane & 31)][kk + (lane >> 5) * 8];
            acc = __builtin_amdgcn_mfma_f32_32x32x16_bf16(ah, bh, acc, 0, 0, 0);
            acc = __builtin_amdgcn_mfma_f32_32x32x16_bf16(ah, bl, acc, 0, 0, 0);
            acc = __builtin_amdgcn_mfma_f32_32x32x16_bf16(al, bh, acc, 0, 0, 0);
        }
        __syncthreads();
    }

    const int n = nw + (lane & 31);
    const int c = ct * 64 + n;
    const float rn = (c < KK) ? sr[c] : rkey[(size_t)b * NN + (c - KK)];
    #pragma unroll
    for (int reg = 0; reg < 16; reg++) {
        int m = mw + (reg & 3) + 8 * (reg >> 2) + 4 * (lane >> 5);
        dots[((size_t)b * KK + m) * CC + c] = acc[reg] * sr[m] * rn;
    }
}

// masked softmax(dots/TEMP), /(1+1e-7), fp32 out. grid (K, B) x 256.
__global__ __launch_bounds__(256) void k_softmax(const float* __restrict__ dots,
                                                 float* __restrict__ attn) {
    const int k = blockIdx.x, b = blockIdx.y;
    const float* row = dots + ((size_t)b * KK + k) * CC;
    float* arow = attn + ((size_t)b * KK + k) * CC;
    const int tid = threadIdx.x;
    __shared__ float red[4];

    float vals[5];
    int cnt = 0;
    float m = -INFINITY;
    for (int c = tid; c < CC; c += 256) {
        bool ok = (c >= KK) || (c < k);   // strict lower-tri for slot-slot, all keys
        float x = ok ? (row[c] / 0.07f) : -INFINITY;
        vals[cnt++] = x;
        m = fmaxf(m, x);
    }
    m = waveReduceMax(m);
    if ((tid & 63) == 0) red[tid >> 6] = m;
    __syncthreads();
    m = fmaxf(fmaxf(red[0], red[1]), fmaxf(red[2], red[3]));

    float s = 0.f;
    cnt = 0;
    for (int c = tid; c < CC; c += 256) {
        float e = (vals[cnt] == -INFINITY) ? 0.0f : expf(vals[cnt] - m);
        vals[cnt] = e;
        s += e;
        cnt++;
    }
    s = waveReduceSum(s);
    __syncthreads();
    if ((tid & 63) == 0) red[tid >> 6] = s;
    __syncthreads();
    s = red[0] + red[1] + red[2] + red[3];

    float inv = 1.0f / (s * (1.0f + 1e-7f));
    cnt = 0;
    for (int c = tid; c < CC; c += 256) arow[c] = vals[cnt++] * inv;
}

// out[b, 0:64, d0:+64] = attn (64xC) x V (CxD), split-bf16 MFMA, V transposed
// in LDS during staging. grid (8, B) x 256.
__global__ __launch_bounds__(256) void k_out(const float* __restrict__ key,
                                             const float* __restrict__ slot,
                                             const float* __restrict__ attn,
                                             float* __restrict__ out) {
    __shared__ __align__(16) bf16_t Ahi[64][72], Alo[64][72];
    __shared__ __align__(16) bf16_t Vhi[64][72], Vlo[64][72];   // [d][c] transposed
    const int b = blockIdx.y, d0 = blockIdx.x * 64;
    const int tid = threadIdx.x;
    const int w = tid >> 6, lane = tid & 63;
    const int mw = (w >> 1) * 32, nw = (w & 1) * 32;
    const int cpair = tid & 31, dg = tid >> 5;    // staging roles for V
    f32x16 acc = {};

    for (int c0 = 0; c0 < CC; c0 += 64) {
        #pragma unroll
        for (int i = 0; i < 4; i++) {
            int idx = tid + i * 256;
            int r = idx >> 4, g = idx & 15;
            float4 av = *(const float4*)&attn[((size_t)b * KK + r) * CC + c0 + g * 4];
            bf16x4 h, l;
            split4(av, h, l);
            *(bf16x4*)&Ahi[r][g * 4] = h;
            *(bf16x4*)&Alo[r][g * 4] = l;
        }
        {   // V transpose: thread owns rows (c, c+1), d-range d0+dg*8 .. +8
            int c = c0 + 2 * cpair;
            const float* r0 = (c < KK)     ? &slot[(size_t)c * DD]
                                           : &key[((size_t)b * NN + (c - KK)) * DD];
            const float* r1 = (c + 1 < KK) ? &slot[(size_t)(c + 1) * DD]
                                           : &key[((size_t)b * NN + (c + 1 - KK)) * DD];
            float4 v0a = *(const float4*)(r0 + d0 + dg * 8);
            float4 v0b = *(const float4*)(r0 + d0 + dg * 8 + 4);
            float4 v1a = *(const float4*)(r1 + d0 + dg * 8);
            float4 v1b = *(const float4*)(r1 + d0 + dg * 8 + 4);
            bf16x4 h0a, l0a, h0b, l0b, h1a, l1a, h1b, l1b;
            split4(v0a, h0a, l0a); split4(v0b, h0b, l0b);
            split4(v1a, h1a, l1a); split4(v1b, h1b, l1b);
            #pragma unroll
            for (int j = 0; j < 8; j++) {
                __bf16 h0 = (j < 4) ? h0a[j] : h0b[j - 4];
                __bf16 l0 = (j < 4) ? l0a[j] : l0b[j - 4];
                __bf16 h1 = (j < 4) ? h1a[j] : h1b[j - 4];
                __bf16 l1 = (j < 4) ? l1a[j] : l1b[j - 4];
                unsigned hw = (unsigned)__builtin_bit_cast(unsigned short, h0)
                            | ((unsigned)__builtin_bit_cast(unsigned short, h1) << 16);
                unsigned lw = (unsigned)__builtin_bit_cast(unsigned short, l0)
                            | ((unsigned)__builtin_bit_cast(unsigned short, l1) << 16);
                *(unsigned*)&Vhi[dg * 8 + j][2 * cpair] = hw;
                *(unsigned*)&Vlo[dg * 8 + j][2 * cpair] = lw;
            }
        }
        __syncthreads();
        #pragma unroll
        for (int kk = 0; kk < 64; kk += 16) {
            bf16x8 ah = *(bf16x8*)&Ahi[mw + (lane & 31)][kk + (lane >> 5) * 8];
            bf16x8 al = *(bf16x8*)&Alo[mw + (lane & 31)][kk + (lane >> 5) * 8];
            bf16x8 vh = *(bf16x8*)&Vhi[nw + (lane & 31)][kk + (lane >> 5) * 8];
            bf16x8 vl = *(bf16x8*)&Vlo[nw + (lane & 31)][kk + (lane >> 5) * 8];
            acc = __builtin_amdgcn_mfma_f32_32x32x16_bf16(ah, vh, acc, 0, 0, 0);
            acc = __builtin_amdgcn_mfma_f32_32x32x16_bf16(ah, vl, acc, 0, 0, 0);
            acc = __builtin_amdgcn_mfma_f32_32x32x16_bf16(al, vh, acc, 0, 0, 0);
        }
        __syncthreads();
    }

    const int d = d0 + nw + (lane & 31);
    #pragma unroll
    for (int reg = 0; reg < 16; reg++) {
        int m = mw + (reg & 3) + 8 * (reg >> 2) + 4 * (lane >> 5);
        out[((size_t)b * KK + m) * DD + d] = acc[reg];
    }
}

extern "C" void kernel_launch(void* const* d_in, const int* in_sizes, int n_in,
                              void* d_out, int out_size, void* d_ws, size_t ws_size,
                              hipStream_t stream) {
    const float* key  = (const float*)d_in[0];   // [B, N, D]
    const float* slot = (const float*)d_in[1];   // [K, D]
    float* out  = (float*)d_out;                        // [B, K, D]
    float* dots = out + (size_t)BB * KK * DD;           // [B, K, C]
    float* ws = (float*)d_ws;
    float* rslot = ws;                                  // [K]
    float* rkey  = ws + 64;                             // [B*N]
    float* attn  = ws + 64 + (size_t)BB * NN;           // [B, K, C] fp32

    k_rslot<<<dim3(KK), dim3(64), 0, stream>>>(slot, rslot);
    k_rkey<<<dim3(BB * NN / 4), dim3(256), 0, stream>>>(key, rkey);
    k_dots<<<dim3(CC / 64, BB), dim3(256), 0, stream>>>(key, slot, rslot, rkey, dots);
    k_softmax<<<dim3(KK, BB), dim3(256), 0, stream>>>(dots, attn);
    k_out<<<dim3(DD / 64, BB), dim3(256), 0, stream>>>(key, slot, attn, out);
}